// Round 6
// baseline (604.540 us; speedup 1.0000x reference)
//
#include <hip/hip_runtime.h>
#include <hip/hip_bf16.h>
#include <hip/hip_fp16.h>
#include <stdint.h>

#define NF 64
#define NC 40
#define ZROW 64        // padded z row: 64 halves = 128 B = 2 full cache lines
#define SCAN_BLK 1024  // elements scanned per block (256 threads x 4)
#define ZB 128         // zgemm: threads (= nodes) per block
#define XPAD 68        // zgemm: padded LDS row stride in floats (16B-aligned b128 reads)

// ---------------------------------------------------------------------------
// Detect whether edge_index was uploaded as int32 or int64.
// For int64 (values < 2^31), every odd 32-bit word is 0.
// flag = 1 -> int32, flag = 0 -> int64.
// ---------------------------------------------------------------------------
__global__ void detect_dtype_kernel(const unsigned int* __restrict__ p, int* __restrict__ flag,
                                    int n_check) {
    __shared__ int s_any;
    if (threadIdx.x == 0) s_any = 0;
    __syncthreads();
    int any = 0;
    for (int i = threadIdx.x; i < n_check; i += blockDim.x) {
        if (p[2 * i + 1] != 0u) any = 1;
    }
    if (any) atomicOr(&s_any, 1);
    __syncthreads();
    if (threadIdx.x == 0) *flag = s_any;
}

__device__ __forceinline__ long long load_idx(const void* p, long long i, int is32) {
    if (is32) return (long long)((const int*)p)[i];
    return ((const long long*)p)[i];
}

__global__ void zero_cnt_kernel(int* __restrict__ cnt, int N) {
    int i = blockIdx.x * blockDim.x + threadIdx.x;
    if (i < N) cnt[i] = 0;
}

// cnt[col[e]] += 1  (in-degree, without self loop)
__global__ void count_kernel(const void* __restrict__ ei, int* __restrict__ cnt,
                             const int* __restrict__ flag, long long E) {
    long long e = (long long)blockIdx.x * blockDim.x + threadIdx.x;
    if (e >= E) return;
    int is32 = *flag;
    int c = (int)load_idx(ei, E + e, is32);
    atomicAdd(&cnt[c], 1);
}

// Per-block exclusive scan of cnt into row_ptr (block-local), block totals -> aux
__global__ void scanA_kernel(const int* __restrict__ cnt, int* __restrict__ row_ptr,
                             int* __restrict__ aux, int N) {
    __shared__ int sd[256];
    int t = threadIdx.x;
    int base = blockIdx.x * SCAN_BLK + t * 4;
    int v[4];
    int s = 0;
#pragma unroll
    for (int j = 0; j < 4; ++j) {
        v[j] = (base + j < N) ? cnt[base + j] : 0;
        s += v[j];
    }
    sd[t] = s;
    __syncthreads();
#pragma unroll
    for (int off = 1; off < 256; off <<= 1) {
        int a = (t >= off) ? sd[t - off] : 0;
        __syncthreads();
        sd[t] += a;
        __syncthreads();
    }
    int run = sd[t] - s;  // exclusive offset of this thread within block
#pragma unroll
    for (int j = 0; j < 4; ++j) {
        if (base + j < N) row_ptr[base + j] = run;
        run += v[j];
    }
    if (t == 255) aux[blockIdx.x] = sd[255];
}

// Exclusive scan of block totals (nb <= 128), single block of 128 threads
__global__ void scanB_kernel(int* __restrict__ aux, int nb) {
    __shared__ int sd[128];
    int t = threadIdx.x;
    int v = (t < nb) ? aux[t] : 0;
    sd[t] = v;
    __syncthreads();
#pragma unroll
    for (int off = 1; off < 128; off <<= 1) {
        int a = (t >= off) ? sd[t - off] : 0;
        __syncthreads();
        sd[t] += a;
        __syncthreads();
    }
    if (t < nb) aux[t] = sd[t] - v;
}

// row_ptr[i] += aux[block(i)]; dinv[i] = rsqrt(1+cnt[i]); cnt[i] = 0 (reused as fill ctr)
__global__ void scanC_kernel(int* __restrict__ row_ptr, const int* __restrict__ aux,
                             int* __restrict__ cnt, float* __restrict__ dinv, int N, int E) {
    int i = blockIdx.x * blockDim.x + threadIdx.x;
    if (i < N) {
        row_ptr[i] += aux[i >> 10];
        int c = cnt[i];
        dinv[i] = rsqrtf(1.0f + (float)c);
        cnt[i] = 0;  // becomes the fill counter
    }
    if (i == 0) row_ptr[N] = E;
}

// csr_src[row_ptr[col]++] = row
__global__ void fill_kernel(const void* __restrict__ ei, const int* __restrict__ row_ptr,
                            int* __restrict__ fill, int* __restrict__ csr_src,
                            const int* __restrict__ flag, long long E) {
    long long e = (long long)blockIdx.x * blockDim.x + threadIdx.x;
    if (e >= E) return;
    int is32 = *flag;
    int r = (int)load_idx(ei, e, is32);
    int c = (int)load_idx(ei, E + e, is32);
    int pos = row_ptr[c] + atomicAdd(&fill[c], 1);
    csr_src[pos] = r;
}

// z[i][c] = half( dinv[i] * sum_f x[i][f] * W[c][f] ), rows padded to 64 halves.
// x staged into LDS coalesced; z staged in LDS (aliasing sX) and flushed with
// full-line coalesced uint4 stores.
__global__ void zgemm_kernel(const float* __restrict__ x, const float* __restrict__ W,
                             const float* __restrict__ dinv, __half* __restrict__ z, int N) {
    __shared__ float4 sW[NC * (NF / 4)];  // 10240 B
    __shared__ union {
        float x[ZB * XPAD];               // 34816 B
        __half zst[ZB * ZROW];            // 16384 B (aliases x)
    } sU;
    for (int i = threadIdx.x; i < NC * (NF / 4); i += ZB)
        sW[i] = ((const float4*)W)[i];

    int base = blockIdx.x * ZB;
    int nrows = N - base;
    if (nrows > ZB) nrows = ZB;
    // coalesced stage: g4-th float4 of this block's x slab -> padded LDS row
    const float4* xg = (const float4*)(x + (size_t)base * NF);
    for (int g4 = threadIdx.x; g4 < nrows * (NF / 4); g4 += ZB) {
        int n = g4 >> 4;
        int i = g4 & 15;
        *((float4*)&sU.x[n * XPAD + i * 4]) = xg[g4];
    }
    __syncthreads();

    int node = base + threadIdx.x;
    float acc[NC];
#pragma unroll
    for (int c = 0; c < NC; ++c) acc[c] = 0.0f;
    float di = 0.0f;

    if (node < N) {
        di = dinv[node];
#pragma unroll
        for (int i = 0; i < NF / 4; ++i) {
            float4 xv = *((const float4*)&sU.x[threadIdx.x * XPAD + i * 4]);
#pragma unroll
            for (int c = 0; c < NC; ++c) {
                float4 w = sW[c * (NF / 4) + i];  // wave-uniform -> broadcast
                acc[c] += w.x * xv.x + w.y * xv.y + w.z * xv.z + w.w * xv.w;
            }
        }
    }
    __syncthreads();  // all sU.x reads done before zst overwrites it

    if (node < N) {
        __half2* zr = (__half2*)&sU.zst[threadIdx.x * ZROW];
#pragma unroll
        for (int p = 0; p < NC / 2; ++p)
            zr[p] = __floats2half2_rn(di * acc[2 * p], di * acc[2 * p + 1]);
#pragma unroll
        for (int p = NC / 2; p < ZROW / 2; ++p)
            zr[p] = __half2{__half(0.0f), __half(0.0f)};  // zero pad
    }
    __syncthreads();

    // flush: nrows * 128 B as uint4 (full 64B lines, fully coalesced)
    uint4* zg = (uint4*)(z + (size_t)base * ZROW);
    const uint4* zs = (const uint4*)sU.zst;
    for (int i = threadIdx.x; i < nrows * (ZROW / 8); i += ZB) zg[i] = zs[i];
}

// One wave per node, all 64 lanes active (rows padded to 64 halves = 2 lines).
// vout[i] = half( dinv[i]^2 * (vin[i] + sum_{s in in(i)} vin[s]) )
__global__ void hop_kernel(const __half* __restrict__ vin, __half* __restrict__ vout,
                           const int* __restrict__ row_ptr, const int* __restrict__ csr_src,
                           const float* __restrict__ dinv, int N) {
    int t = blockIdx.x * blockDim.x + threadIdx.x;
    int node = t >> 6;
    int lane = t & 63;
    if (node >= N) return;
    int beg = row_ptr[node];
    int end = row_ptr[node + 1];
    int deg = end - beg;

    float acc = __half2float(vin[(size_t)node * ZROW + lane]);  // pad lanes read 0

    int idx = 0;
    if (beg + lane < end) idx = csr_src[beg + lane];

    int m = (deg < 64) ? deg : 64;
#pragma unroll 4
    for (int k = 0; k < m; ++k) {
        int s = __shfl(idx, k);
        acc += __half2float(vin[(size_t)s * ZROW + lane]);
    }
    for (int k = 64; k < deg; ++k) {  // ~never taken (Poisson lambda=12.5)
        int s = csr_src[beg + k];
        acc += __half2float(vin[(size_t)s * ZROW + lane]);
    }

    float di = dinv[node];
    // all 64 lanes store -> one full 128B aligned span per node (pad stays 0)
    vout[(size_t)node * ZROW + lane] = __float2half(di * di * acc);
}

// Final hop fused with bias + relu + log_softmax. Output rows staged in LDS and
// flushed coalesced (640 B = 10 full lines per 256-thread block).
__global__ void hop_final_kernel(const __half* __restrict__ vin, const float* __restrict__ b,
                                 float* __restrict__ out, const int* __restrict__ row_ptr,
                                 const int* __restrict__ csr_src, const float* __restrict__ dinv,
                                 int N) {
    __shared__ float sOut[4 * NC];
    int node = (blockIdx.x * blockDim.x + threadIdx.x) >> 6;
    int lane = threadIdx.x & 63;
    int wid = threadIdx.x >> 6;

    if (node < N) {
        int beg = row_ptr[node];
        int end = row_ptr[node + 1];
        int deg = end - beg;

        float acc = __half2float(vin[(size_t)node * ZROW + lane]);

        int idx = 0;
        if (beg + lane < end) idx = csr_src[beg + lane];

        int m = (deg < 64) ? deg : 64;
#pragma unroll 4
        for (int k = 0; k < m; ++k) {
            int s = __shfl(idx, k);
            acc += __half2float(vin[(size_t)s * ZROW + lane]);
        }
        for (int k = 64; k < deg; ++k) {
            int s = csr_src[beg + k];
            acc += __half2float(vin[(size_t)s * ZROW + lane]);
        }

        float di = dinv[node];
        float bv = (lane < NC) ? b[lane] : 0.0f;
        float l = di * acc + bv;           // pad lanes: acc=0, bv=0 -> l=0
        l = fmaxf(l, 0.0f);

        // max over lanes (post-relu values >= 0; pad lanes hold 0 -> harmless)
        float lm = l;
#pragma unroll
        for (int off = 32; off > 0; off >>= 1) lm = fmaxf(lm, __shfl_xor(lm, off));
        float e = (lane < NC) ? __expf(l - lm) : 0.0f;
#pragma unroll
        for (int off = 32; off > 0; off >>= 1) e += __shfl_xor(e, off);
        float lse = lm + __logf(e);

        if (lane < NC) sOut[wid * NC + lane] = l - lse;
    }
    __syncthreads();

    int base_node = blockIdx.x * 4;
    int nval = N - base_node;
    if (nval > 4) nval = 4;
    if (nval < 0) nval = 0;
    float* op = out + (size_t)base_node * NC;
    for (int i = threadIdx.x; i < nval * NC; i += 256) op[i] = sOut[i];
}

extern "C" void kernel_launch(void* const* d_in, const int* in_sizes, int n_in,
                              void* d_out, int out_size, void* d_ws, size_t ws_size,
                              hipStream_t stream) {
    const float* x = (const float*)d_in[0];
    const void* ei = d_in[1];
    const float* W = (const float*)d_in[2];
    const float* b = (const float*)d_in[3];
    float* out = (float*)d_out;

    const int N = in_sizes[0] / NF;          // 100000
    const long long E = in_sizes[1] / 2;     // 1250000

    // workspace layout (256B aligned chunks)
    size_t off = 0;
    int* flag = (int*)((char*)d_ws + off);
    off += 256;
    int* cnt = (int*)((char*)d_ws + off);           // later reused as fill counters
    off += ((size_t)N * 4 + 255) & ~(size_t)255;
    int* row_ptr = (int*)((char*)d_ws + off);
    off += ((size_t)(N + 1) * 4 + 255) & ~(size_t)255;
    int* aux = (int*)((char*)d_ws + off);
    off += 1024;
    float* dinv = (float*)((char*)d_ws + off);
    off += ((size_t)N * 4 + 255) & ~(size_t)255;
    int* csr_src = (int*)((char*)d_ws + off);
    off += ((size_t)E * 4 + 255) & ~(size_t)255;
    __half* z1 = (__half*)((char*)d_ws + off);
    off += ((size_t)N * ZROW * 2 + 255) & ~(size_t)255;  // 128B rows
    __half* z2 = (__half*)((char*)d_ws + off);
    off += ((size_t)N * ZROW * 2 + 255) & ~(size_t)255;
    if (off > ws_size) return;  // insufficient workspace

    const int B = 256;
    int gridN = (N + B - 1) / B;
    int gridE = (int)((E + B - 1) / B);
    int nScanBlocks = (N + SCAN_BLK - 1) / SCAN_BLK;  // 98
    int gridW = (int)(((long long)N * 64 + B - 1) / B);  // wave per node

    // 0. dtype detection
    int n_check = (int)((E < 4096) ? E : 4096);
    detect_dtype_kernel<<<1, 256, 0, stream>>>((const unsigned int*)ei, flag, n_check);

    // 1. CSR build: count -> scan -> fill ; dinv from degrees
    zero_cnt_kernel<<<gridN, B, 0, stream>>>(cnt, N);
    count_kernel<<<gridE, B, 0, stream>>>(ei, cnt, flag, E);
    scanA_kernel<<<nScanBlocks, 256, 0, stream>>>(cnt, row_ptr, aux, N);
    scanB_kernel<<<1, 128, 0, stream>>>(aux, nScanBlocks);
    scanC_kernel<<<gridN, B, 0, stream>>>(row_ptr, aux, cnt, dinv, N, (int)E);
    fill_kernel<<<gridE, B, 0, stream>>>(ei, row_ptr, cnt, csr_src, flag, E);

    // 2. v0 = D^{-1/2} (x W^T)   [N,64-padded] in fp16
    zgemm_kernel<<<(N + ZB - 1) / ZB, ZB, 0, stream>>>(x, W, dinv, z1, N);

    // 3. hops 1,2 in class space (fp16); hop 3 fused with bias+relu+log_softmax
    hop_kernel<<<gridW, B, 0, stream>>>(z1, z2, row_ptr, csr_src, dinv, N);
    hop_kernel<<<gridW, B, 0, stream>>>(z2, z1, row_ptr, csr_src, dinv, N);
    hop_final_kernel<<<gridW, B, 0, stream>>>(z1, b, out, row_ptr, csr_src, dinv, N);
}

// Round 7
// 441.869 us; speedup vs baseline: 1.3681x; 1.3681x over previous
//
#include <hip/hip_runtime.h>
#include <hip/hip_bf16.h>
#include <hip/hip_fp16.h>
#include <stdint.h>

#define NF 64
#define NC 40
#define ZROW 64        // padded z row: 64 halves = 128 B = 2 full cache lines
#define SCAN_BLK 1024  // elements scanned per block (256 threads x 4)

// ---------------------------------------------------------------------------
// Detect whether edge_index was uploaded as int32 or int64.
// For int64 (values < 2^31), every odd 32-bit word is 0.
// flag = 1 -> int32, flag = 0 -> int64.
// ---------------------------------------------------------------------------
__global__ void detect_dtype_kernel(const unsigned int* __restrict__ p, int* __restrict__ flag,
                                    int n_check) {
    __shared__ int s_any;
    if (threadIdx.x == 0) s_any = 0;
    __syncthreads();
    int any = 0;
    for (int i = threadIdx.x; i < n_check; i += blockDim.x) {
        if (p[2 * i + 1] != 0u) any = 1;
    }
    if (any) atomicOr(&s_any, 1);
    __syncthreads();
    if (threadIdx.x == 0) *flag = s_any;
}

__device__ __forceinline__ long long load_idx(const void* p, long long i, int is32) {
    if (is32) return (long long)((const int*)p)[i];
    return ((const long long*)p)[i];
}

__global__ void zero_cnt_kernel(int* __restrict__ cnt, int N) {
    int i = blockIdx.x * blockDim.x + threadIdx.x;
    if (i < N) cnt[i] = 0;
}

// cnt[col[e]] += 1  (in-degree, without self loop)
__global__ void count_kernel(const void* __restrict__ ei, int* __restrict__ cnt,
                             const int* __restrict__ flag, long long E) {
    long long e = (long long)blockIdx.x * blockDim.x + threadIdx.x;
    if (e >= E) return;
    int is32 = *flag;
    int c = (int)load_idx(ei, E + e, is32);
    atomicAdd(&cnt[c], 1);
}

// Per-block exclusive scan of cnt into row_ptr (block-local), block totals -> aux
__global__ void scanA_kernel(const int* __restrict__ cnt, int* __restrict__ row_ptr,
                             int* __restrict__ aux, int N) {
    __shared__ int sd[256];
    int t = threadIdx.x;
    int base = blockIdx.x * SCAN_BLK + t * 4;
    int v[4];
    int s = 0;
#pragma unroll
    for (int j = 0; j < 4; ++j) {
        v[j] = (base + j < N) ? cnt[base + j] : 0;
        s += v[j];
    }
    sd[t] = s;
    __syncthreads();
#pragma unroll
    for (int off = 1; off < 256; off <<= 1) {
        int a = (t >= off) ? sd[t - off] : 0;
        __syncthreads();
        sd[t] += a;
        __syncthreads();
    }
    int run = sd[t] - s;  // exclusive offset of this thread within block
#pragma unroll
    for (int j = 0; j < 4; ++j) {
        if (base + j < N) row_ptr[base + j] = run;
        run += v[j];
    }
    if (t == 255) aux[blockIdx.x] = sd[255];
}

// Exclusive scan of block totals (nb <= 128), single block of 128 threads
__global__ void scanB_kernel(int* __restrict__ aux, int nb) {
    __shared__ int sd[128];
    int t = threadIdx.x;
    int v = (t < nb) ? aux[t] : 0;
    sd[t] = v;
    __syncthreads();
#pragma unroll
    for (int off = 1; off < 128; off <<= 1) {
        int a = (t >= off) ? sd[t - off] : 0;
        __syncthreads();
        sd[t] += a;
        __syncthreads();
    }
    if (t < nb) aux[t] = sd[t] - v;
}

// row_ptr[i] += aux[block(i)]; dinv[i] = rsqrt(1+cnt[i]); cnt[i] = 0 (reused as fill ctr)
__global__ void scanC_kernel(int* __restrict__ row_ptr, const int* __restrict__ aux,
                             int* __restrict__ cnt, float* __restrict__ dinv, int N, int E) {
    int i = blockIdx.x * blockDim.x + threadIdx.x;
    if (i < N) {
        row_ptr[i] += aux[i >> 10];
        int c = cnt[i];
        dinv[i] = rsqrtf(1.0f + (float)c);
        cnt[i] = 0;  // becomes the fill counter
    }
    if (i == 0) row_ptr[N] = E;
}

// csr_src[row_ptr[col]++] = row
__global__ void fill_kernel(const void* __restrict__ ei, const int* __restrict__ row_ptr,
                            int* __restrict__ fill, int* __restrict__ csr_src,
                            const int* __restrict__ flag, long long E) {
    long long e = (long long)blockIdx.x * blockDim.x + threadIdx.x;
    if (e >= E) return;
    int is32 = *flag;
    int r = (int)load_idx(ei, e, is32);
    int c = (int)load_idx(ei, E + e, is32);
    int pos = row_ptr[c] + atomicAdd(&fill[c], 1);
    csr_src[pos] = r;
}

// z[i][c] = half( dinv[i] * sum_f x[i][f] * W[c][f] ), rows padded to 64 halves.
// Spill-proof structure: one wave per node; lane c owns class c; W row c in
// 64 VGPRs (static indexing); x row read via wave-uniform pointer (scalarizes
// to s_load); store = 64 lanes x 2B = one coalesced 128B row. No LDS, no arrays.
__global__ __launch_bounds__(256, 2)
void zgemm_kernel(const float* __restrict__ x, const float* __restrict__ W,
                  const float* __restrict__ dinv, __half* __restrict__ z, int N) {
    int lane = threadIdx.x & 63;
    int gwave = (blockIdx.x * blockDim.x + threadIdx.x) >> 6;
    int nwaves = (gridDim.x * blockDim.x) >> 6;

    int c = (lane < NC) ? lane : (NC - 1);  // clamp pad lanes to a valid row
    float wreg[NF];
    const float4* wr = (const float4*)(W + (size_t)c * NF);
#pragma unroll
    for (int i = 0; i < NF / 4; ++i) {
        float4 wv = wr[i];
        wreg[4 * i + 0] = wv.x;
        wreg[4 * i + 1] = wv.y;
        wreg[4 * i + 2] = wv.z;
        wreg[4 * i + 3] = wv.w;
    }

    for (int node = gwave; node < N; node += nwaves) {
        int un = __builtin_amdgcn_readfirstlane(node);  // force wave-uniform
        const float* xr = x + (size_t)un * NF;
        float a0 = 0.f, a1 = 0.f, a2 = 0.f, a3 = 0.f;  // break the dep chain
#pragma unroll
        for (int k = 0; k < NF; k += 4) {
            a0 += xr[k + 0] * wreg[k + 0];
            a1 += xr[k + 1] * wreg[k + 1];
            a2 += xr[k + 2] * wreg[k + 2];
            a3 += xr[k + 3] * wreg[k + 3];
        }
        float acc = (a0 + a1) + (a2 + a3);
        float di = dinv[un];
        float v = (lane < NC) ? di * acc : 0.0f;  // pad lanes write 0
        z[(size_t)un * ZROW + lane] = __float2half(v);
    }
}

// One wave per node, all 64 lanes active (rows padded to 64 halves = 2 lines).
// vout[i] = half( dinv[i]^2 * (vin[i] + sum_{s in in(i)} vin[s]) )
__global__ void hop_kernel(const __half* __restrict__ vin, __half* __restrict__ vout,
                           const int* __restrict__ row_ptr, const int* __restrict__ csr_src,
                           const float* __restrict__ dinv, int N) {
    int t = blockIdx.x * blockDim.x + threadIdx.x;
    int node = t >> 6;
    int lane = t & 63;
    if (node >= N) return;
    int beg = row_ptr[node];
    int end = row_ptr[node + 1];
    int deg = end - beg;

    float acc = __half2float(vin[(size_t)node * ZROW + lane]);  // pad lanes read 0

    int idx = 0;
    if (beg + lane < end) idx = csr_src[beg + lane];

    int m = (deg < 64) ? deg : 64;
#pragma unroll 4
    for (int k = 0; k < m; ++k) {
        int s = __shfl(idx, k);
        acc += __half2float(vin[(size_t)s * ZROW + lane]);
    }
    for (int k = 64; k < deg; ++k) {  // ~never taken (Poisson lambda=12.5)
        int s = csr_src[beg + k];
        acc += __half2float(vin[(size_t)s * ZROW + lane]);
    }

    float di = dinv[node];
    // all 64 lanes store -> one full 128B aligned span per node (pad stays 0)
    vout[(size_t)node * ZROW + lane] = __float2half(di * di * acc);
}

// Final hop fused with bias + relu + log_softmax. Output rows staged in LDS and
// flushed coalesced (640 B = 10 full lines per 256-thread block).
__global__ void hop_final_kernel(const __half* __restrict__ vin, const float* __restrict__ b,
                                 float* __restrict__ out, const int* __restrict__ row_ptr,
                                 const int* __restrict__ csr_src, const float* __restrict__ dinv,
                                 int N) {
    __shared__ float sOut[4 * NC];
    int node = (blockIdx.x * blockDim.x + threadIdx.x) >> 6;
    int lane = threadIdx.x & 63;
    int wid = threadIdx.x >> 6;

    if (node < N) {
        int beg = row_ptr[node];
        int end = row_ptr[node + 1];
        int deg = end - beg;

        float acc = __half2float(vin[(size_t)node * ZROW + lane]);

        int idx = 0;
        if (beg + lane < end) idx = csr_src[beg + lane];

        int m = (deg < 64) ? deg : 64;
#pragma unroll 4
        for (int k = 0; k < m; ++k) {
            int s = __shfl(idx, k);
            acc += __half2float(vin[(size_t)s * ZROW + lane]);
        }
        for (int k = 64; k < deg; ++k) {
            int s = csr_src[beg + k];
            acc += __half2float(vin[(size_t)s * ZROW + lane]);
        }

        float di = dinv[node];
        float bv = (lane < NC) ? b[lane] : 0.0f;
        float l = di * acc + bv;           // pad lanes: acc=0, bv=0 -> l=0
        l = fmaxf(l, 0.0f);

        // max over lanes (post-relu values >= 0; pad lanes hold 0 -> harmless)
        float lm = l;
#pragma unroll
        for (int off = 32; off > 0; off >>= 1) lm = fmaxf(lm, __shfl_xor(lm, off));
        float e = (lane < NC) ? __expf(l - lm) : 0.0f;
#pragma unroll
        for (int off = 32; off > 0; off >>= 1) e += __shfl_xor(e, off);
        float lse = lm + __logf(e);

        if (lane < NC) sOut[wid * NC + lane] = l - lse;
    }
    __syncthreads();

    int base_node = blockIdx.x * 4;
    int nval = N - base_node;
    if (nval > 4) nval = 4;
    if (nval < 0) nval = 0;
    float* op = out + (size_t)base_node * NC;
    for (int i = threadIdx.x; i < nval * NC; i += 256) op[i] = sOut[i];
}

extern "C" void kernel_launch(void* const* d_in, const int* in_sizes, int n_in,
                              void* d_out, int out_size, void* d_ws, size_t ws_size,
                              hipStream_t stream) {
    const float* x = (const float*)d_in[0];
    const void* ei = d_in[1];
    const float* W = (const float*)d_in[2];
    const float* b = (const float*)d_in[3];
    float* out = (float*)d_out;

    const int N = in_sizes[0] / NF;          // 100000
    const long long E = in_sizes[1] / 2;     // 1250000

    // workspace layout (256B aligned chunks)
    size_t off = 0;
    int* flag = (int*)((char*)d_ws + off);
    off += 256;
    int* cnt = (int*)((char*)d_ws + off);           // later reused as fill counters
    off += ((size_t)N * 4 + 255) & ~(size_t)255;
    int* row_ptr = (int*)((char*)d_ws + off);
    off += ((size_t)(N + 1) * 4 + 255) & ~(size_t)255;
    int* aux = (int*)((char*)d_ws + off);
    off += 1024;
    float* dinv = (float*)((char*)d_ws + off);
    off += ((size_t)N * 4 + 255) & ~(size_t)255;
    int* csr_src = (int*)((char*)d_ws + off);
    off += ((size_t)E * 4 + 255) & ~(size_t)255;
    __half* z1 = (__half*)((char*)d_ws + off);
    off += ((size_t)N * ZROW * 2 + 255) & ~(size_t)255;  // 128B rows
    __half* z2 = (__half*)((char*)d_ws + off);
    off += ((size_t)N * ZROW * 2 + 255) & ~(size_t)255;
    if (off > ws_size) return;  // insufficient workspace

    const int B = 256;
    int gridN = (N + B - 1) / B;
    int gridE = (int)((E + B - 1) / B);
    int nScanBlocks = (N + SCAN_BLK - 1) / SCAN_BLK;  // 98
    int gridW = (int)(((long long)N * 64 + B - 1) / B);  // wave per node

    // 0. dtype detection
    int n_check = (int)((E < 4096) ? E : 4096);
    detect_dtype_kernel<<<1, 256, 0, stream>>>((const unsigned int*)ei, flag, n_check);

    // 1. CSR build: count -> scan -> fill ; dinv from degrees
    zero_cnt_kernel<<<gridN, B, 0, stream>>>(cnt, N);
    count_kernel<<<gridE, B, 0, stream>>>(ei, cnt, flag, E);
    scanA_kernel<<<nScanBlocks, 256, 0, stream>>>(cnt, row_ptr, aux, N);
    scanB_kernel<<<1, 128, 0, stream>>>(aux, nScanBlocks);
    scanC_kernel<<<gridN, B, 0, stream>>>(row_ptr, aux, cnt, dinv, N, (int)E);
    fill_kernel<<<gridE, B, 0, stream>>>(ei, row_ptr, cnt, csr_src, flag, E);

    // 2. v0 = D^{-1/2} (x W^T)   [N,64-padded] in fp16
    //    1024 blocks x 4 waves = 4096 waves, grid-stride over nodes
    zgemm_kernel<<<1024, 256, 0, stream>>>(x, W, dinv, z1, N);

    // 3. hops 1,2 in class space (fp16); hop 3 fused with bias+relu+log_softmax
    hop_kernel<<<gridW, B, 0, stream>>>(z1, z2, row_ptr, csr_src, dinv, N);
    hop_kernel<<<gridW, B, 0, stream>>>(z2, z1, row_ptr, csr_src, dinv, N);
    hop_final_kernel<<<gridW, B, 0, stream>>>(z1, b, out, row_ptr, csr_src, dinv, N);
}